// Round 6
// baseline (536.508 us; speedup 1.0000x reference)
//
#include <hip/hip_runtime.h>

// ---------------------------------------------------------------------------
// AttnPool: out[1,768] = mean_rows( softmax(QK^T/16) @ V ) @ Wo^T
// M=16384, D=768, H=256.  a_bar[j] = (1/M) sum_m exp(S[m,j]/16)/rowsum[m];
// out = (a_bar @ V) @ Wo^T.
//
// R5 counters: pass1/pass2 = 202us each @ MfmaUtil 30%, bank-conflict 1.68e7
// (the m97 2-phase ceiling). This round: S-passes rewritten as a 256^2-tile,
// BK=64, 8-wave kernel with counted-vmcnt pipeline (T3/T4), LDS XOR-swizzle
// (T2), setprio (T5). Per K-tile: stage(t+1); vmcnt(8); barrier; reads+MFMA;
// barrier.  Proof: barrier2(t-1) frees buf[(t+1)&1] globally before stage
// issues; vmcnt(8)+barrier1 certifies stage(t) landed across waves. Pipeline
// never drains (epilogues are register-only), runs across col-tiles.
// ---------------------------------------------------------------------------

typedef unsigned short u16;
typedef __attribute__((ext_vector_type(8))) unsigned short u16x8;
typedef __bf16 bf16x8 __attribute__((ext_vector_type(8)));
typedef float f32x4 __attribute__((ext_vector_type(4)));

#define MTOK 16384
#define DDIM 768
#define HDIM 256
#define SM_SCALE 0.0625f   // 1/sqrt(256)

// ---- workspace layout (bytes) ----
#define OFF_XB    (size_t)0                       // bf16 x      [M][768]
#define OFF_WCAT  (size_t)25165824                // bf16 Wcat   [768][768]
#define OFF_QB    (size_t)26345472                // bf16 Q      [M][256]
#define OFF_KB    (size_t)34734080                // bf16 K      [M][256]
#define OFF_VF    (size_t)43122688                // f32  V      [M][256]
#define OFF_RS    (size_t)59899904                // f32 rowsum  [M]
#define OFF_RINV  (size_t)59965440                // f32 rinv    [M]
#define OFF_CA    (size_t)60030976                // f32 colacc  [M]
#define OFF_P     (size_t)60096512                // f32 p       [256]
#define WS_NEED   (size_t)60097536

__device__ __forceinline__ u16 f2bf(float f) {
  union { float f; unsigned u; } v; v.f = f;
  unsigned r = v.u + 0x7fffu + ((v.u >> 16) & 1u);
  return (u16)(r >> 16);
}

// ---------------- fp32 -> bf16 conversion, 8 elems/thread -------------------
__global__ void k_conv(const float* __restrict__ src, u16* __restrict__ dst, int n8) {
  int i = blockIdx.x * blockDim.x + threadIdx.x;
  if (i >= n8) return;
  const float4* s = (const float4*)src;
  float4 a = s[2 * i], b = s[2 * i + 1];
  u16x8 o = { f2bf(a.x), f2bf(a.y), f2bf(a.z), f2bf(a.w),
              f2bf(b.x), f2bf(b.y), f2bf(b.z), f2bf(b.w) };
  *(u16x8*)(dst + (size_t)i * 8) = o;
}

// ===================== QKV projection (m97 structure, unchanged) ============
__device__ __forceinline__ void stage_tile(const u16* __restrict__ g, int ld,
                                           u16* lds, int wid, int lane) {
  const int r = lane >> 2;
  const int c = (lane & 3) * 8;
#pragma unroll
  for (int i = 0; i < 2; ++i) {
    int ii = wid * 2 + i;
    const u16* gp = g + (size_t)(ii * 16 + r) * ld + c;
    __builtin_amdgcn_global_load_lds(
        (const __attribute__((address_space(1))) unsigned int*)gp,
        (__attribute__((address_space(3))) unsigned int*)(lds + ii * 512),
        16, 0, 0);
  }
}

#define KSTEP(APTR, LDA, BPTR, LDB)                                           \
  {                                                                           \
    stage_tile((APTR), (LDA), As, wid, lane);                                 \
    stage_tile((BPTR), (LDB), Bs, wid, lane);                                 \
    __syncthreads();                                                          \
    bf16x8 af[4], bfr[4];                                                     \
    const int kk = (lane >> 4) * 8;                                           \
    _Pragma("unroll") for (int m = 0; m < 4; ++m)                             \
        af[m] = *(const bf16x8*)(As + (wm * 64 + m * 16 + (lane & 15)) * 32 + kk); \
    _Pragma("unroll") for (int n = 0; n < 4; ++n)                             \
        bfr[n] = *(const bf16x8*)(Bs + (wn * 64 + n * 16 + (lane & 15)) * 32 + kk); \
    _Pragma("unroll") for (int m = 0; m < 4; ++m)                             \
        _Pragma("unroll") for (int n = 0; n < 4; ++n)                         \
            acc[m][n] = __builtin_amdgcn_mfma_f32_16x16x32_bf16(              \
                af[m], bfr[n], acc[m][n], 0, 0, 0);                           \
    __syncthreads();                                                          \
  }

__global__ __launch_bounds__(256, 2) void k_qkv(const u16* __restrict__ Xb,
                                                const u16* __restrict__ Wcat,
                                                u16* __restrict__ Qb,
                                                u16* __restrict__ Kb,
                                                float* __restrict__ Vf) {
  __shared__ u16 As[128 * 32];
  __shared__ u16 Bs[128 * 32];
  const int tid = threadIdx.x, wid = tid >> 6, lane = tid & 63;
  const int wm = wid >> 1, wn = wid & 1;
  const int row0 = blockIdx.x * 128;
  const int col0 = blockIdx.y * 128;
  f32x4 acc[4][4] = {};
  for (int k0 = 0; k0 < DDIM; k0 += 32) {
    KSTEP(Xb + (size_t)row0 * DDIM + k0, DDIM,
          Wcat + (size_t)col0 * DDIM + k0, DDIM);
  }
#pragma unroll
  for (int m = 0; m < 4; ++m)
#pragma unroll
    for (int n = 0; n < 4; ++n) {
      int col = col0 + wn * 64 + n * 16 + (lane & 15);
#pragma unroll
      for (int j = 0; j < 4; ++j) {
        int row = row0 + wm * 64 + m * 16 + (lane >> 4) * 4 + j;
        float v = acc[m][n][j];
        if (col < 256)      Qb[(size_t)row * HDIM + col]         = f2bf(v);
        else if (col < 512) Kb[(size_t)row * HDIM + (col - 256)] = f2bf(v);
        else                Vf[(size_t)row * HDIM + (col - 512)] = v;
      }
    }
}

// ===================== S-pass: 256^2 tile, BK=64, counted-vmcnt pipeline ====
// Block: 512 thr (8 waves, 2M x 4N), per-wave 128x64 out, acc[8][4] f32x4.
// LDS: 2 bufs x (A[256][64] + B[256][64]) bf16 = 128KB.
// T2 swizzle: byte ^= ((row&7)<<4) within 128B rows; linear LDS dest +
// pre-swizzled global source (gload_lds) + swizzled ds_read.
// Grid: 512 blocks = 64 row-panels x 8 col-groups; each block walks 8
// col-tiles x 4 K-tiles = 32 K-tiles with one continuous pipeline.
// PASS 1: rowsum atomics at kernel end. PASS 2: rinv-weighted col atomics
// per col-tile.

__device__ __forceinline__ void stage_kt(u16* sh, const u16* __restrict__ Qb,
                                         const u16* __restrict__ Kb,
                                         int rp, int cg, int wid, int srow,
                                         int wsrc, int t) {
  const int kb = (t & 3) * 128;            // byte offset of K-cols in a row
  u16* dst = sh + (t & 1) * 32768;         // u16 units: 64KB per buffer
  if (wid < 4) {                           // A: Q rows rp*256..+255
    const char* base = (const char*)Qb + (size_t)(rp * 256) * 512 + kb + wsrc;
#pragma unroll
    for (int j = 0; j < 8; ++j) {
      int c = wid * 8 + j;                 // chunk 0..31, 1KB each
      int row = c * 8 + srow;
      __builtin_amdgcn_global_load_lds(
          (const __attribute__((address_space(1))) unsigned int*)(base + (size_t)row * 512),
          (__attribute__((address_space(3))) unsigned int*)(dst + c * 512),
          16, 0, 0);
    }
  } else {                                 // B: K rows ct*256..+255
    const int ct = cg * 8 + (t >> 2);
    const char* base = (const char*)Kb + (size_t)(ct * 256) * 512 + kb + wsrc;
#pragma unroll
    for (int j = 0; j < 8; ++j) {
      int c = (wid - 4) * 8 + j;
      int row = c * 8 + srow;
      __builtin_amdgcn_global_load_lds(
          (const __attribute__((address_space(1))) unsigned int*)(base + (size_t)row * 512),
          (__attribute__((address_space(3))) unsigned int*)(dst + 16384 + c * 512),
          16, 0, 0);
    }
  }
}

template <int PASS>
__global__ __launch_bounds__(512, 2) void k_spass(const u16* __restrict__ Qb,
                                                  const u16* __restrict__ Kb,
                                                  const float* __restrict__ rinv,
                                                  float* __restrict__ dst) {
  __shared__ u16 sh[65536];                // 128KB: 2 x (A 32KB + B 32KB)
  const int tid = threadIdx.x, wid = tid >> 6, lane = tid & 63;
  const int wm = wid >> 2, wn = wid & 3;
  const int rp = blockIdx.x >> 3;          // row-panel (64)
  const int cg = blockIdx.x & 7;           // col-group (8) -> XCD locality

  // ds_read swizzled within-row offsets (u16 units) for kk=0/1
  const int colp = (lane >> 4) * 16;             // bytes
  const int swzr = (lane & 7) << 4;              // bytes
  const int rd0 = ((0  + colp) ^ swzr) >> 1;
  const int rd1 = ((64 + colp) ^ swzr) >> 1;
  // stage source pre-swizzle
  const int srow = lane >> 3;
  const int wsrc = ((lane & 7) ^ srow) << 4;

  f32x4 acc[8][4] = {};
  float aux[8][4];                          // PASS1: row exp-sums; PASS2: rinv
#pragma unroll
  for (int mi = 0; mi < 8; ++mi)
#pragma unroll
    for (int j = 0; j < 4; ++j)
      aux[mi][j] = (PASS == 1) ? 0.0f
          : rinv[rp * 256 + wm * 128 + mi * 16 + (lane >> 4) * 4 + j];

  stage_kt(sh, Qb, Kb, rp, cg, wid, srow, wsrc, 0);   // prologue

  for (int t = 0; t < 32; ++t) {
    if (t + 1 < 32) {
      stage_kt(sh, Qb, Kb, rp, cg, wid, srow, wsrc, t + 1);
      asm volatile("s_waitcnt vmcnt(8)" ::: "memory");   // own stage(t) landed
    } else {
      asm volatile("s_waitcnt vmcnt(0)" ::: "memory");
    }
    __builtin_amdgcn_s_barrier();           // all waves' stage(t) landed

    const int base = (t & 1) * 32768;
    const u16* Ab = sh + base;
    const u16* Bb = sh + base + 16384;

    bf16x8 bq[4][2];
#pragma unroll
    for (int ni = 0; ni < 4; ++ni) {
      const int rb = (wn * 64 + ni * 16 + (lane & 15)) * 64;
      bq[ni][0] = *(const bf16x8*)(Bb + rb + rd0);
      bq[ni][1] = *(const bf16x8*)(Bb + rb + rd1);
    }
    __builtin_amdgcn_s_setprio(1);
#pragma unroll
    for (int mi = 0; mi < 8; ++mi) {
      const int ra = (wm * 128 + mi * 16 + (lane & 15)) * 64;
      bf16x8 a0 = *(const bf16x8*)(Ab + ra + rd0);
      bf16x8 a1 = *(const bf16x8*)(Ab + ra + rd1);
#pragma unroll
      for (int ni = 0; ni < 4; ++ni) {
        acc[mi][ni] = __builtin_amdgcn_mfma_f32_16x16x32_bf16(a0, bq[ni][0], acc[mi][ni], 0, 0, 0);
        acc[mi][ni] = __builtin_amdgcn_mfma_f32_16x16x32_bf16(a1, bq[ni][1], acc[mi][ni], 0, 0, 0);
      }
    }
    __builtin_amdgcn_s_setprio(0);
    __builtin_amdgcn_s_barrier();           // all reads of buf[t&1] done

    if ((t & 3) == 3) {                     // col-tile epilogue (register-only)
      if (PASS == 1) {
#pragma unroll
        for (int mi = 0; mi < 8; ++mi)
#pragma unroll
          for (int ni = 0; ni < 4; ++ni)
#pragma unroll
            for (int j = 0; j < 4; ++j)
              aux[mi][j] += __expf(acc[mi][ni][j] * SM_SCALE);
      } else {
        const int ct = cg * 8 + (t >> 2);
        float cs[4] = {};
#pragma unroll
        for (int mi = 0; mi < 8; ++mi)
#pragma unroll
          for (int ni = 0; ni < 4; ++ni)
#pragma unroll
            for (int j = 0; j < 4; ++j)
              cs[ni] += __expf(acc[mi][ni][j] * SM_SCALE) * aux[mi][j];
#pragma unroll
        for (int ni = 0; ni < 4; ++ni) {
          float v = cs[ni];
          v += __shfl_xor(v, 16);
          v += __shfl_xor(v, 32);
          if ((lane >> 4) == 0)
            atomicAdd(&dst[ct * 256 + wn * 64 + ni * 16 + (lane & 15)], v);
        }
      }
#pragma unroll
      for (int mi = 0; mi < 8; ++mi)
#pragma unroll
        for (int ni = 0; ni < 4; ++ni)
          acc[mi][ni] = (f32x4){0.f, 0.f, 0.f, 0.f};
    }
  }

  if (PASS == 1) {
#pragma unroll
    for (int mi = 0; mi < 8; ++mi)
#pragma unroll
      for (int j = 0; j < 4; ++j) {
        float v = aux[mi][j];
        v += __shfl_xor(v, 1);  v += __shfl_xor(v, 2);
        v += __shfl_xor(v, 4);  v += __shfl_xor(v, 8);
        if ((lane & 15) == 0)
          atomicAdd(&dst[rp * 256 + wm * 128 + mi * 16 + (lane >> 4) * 4 + j], v);
      }
  }
}

__global__ void k_rinv(const float* __restrict__ rowsum, float* __restrict__ rinv) {
  int i = blockIdx.x * 256 + threadIdx.x;
  if (i < MTOK) rinv[i] = 1.0f / (rowsum[i] * (float)MTOK);
}

// --------------------- tail reductions --------------------------------------
__global__ void k_p(const float* __restrict__ colacc, const float* __restrict__ Vf,
                    float* __restrict__ p) {
  const int h = threadIdx.x;
  const int r0 = blockIdx.x * 128;
  float s = 0.f;
  for (int r = r0; r < r0 + 128; ++r)
    s += colacc[r] * Vf[(size_t)r * HDIM + h];
  atomicAdd(&p[h], s);
}

__global__ void k_out(const float* __restrict__ p, const float* __restrict__ Wo,
                      float* __restrict__ out) {
  const int d = blockIdx.x * 256 + threadIdx.x;
  if (d >= DDIM) return;
  float s = 0.f;
  for (int h = 0; h < HDIM; ++h) s += p[h] * Wo[(size_t)d * HDIM + h];
  out[d] = s;
}

// ---------------------------------------------------------------------------
extern "C" void kernel_launch(void* const* d_in, const int* in_sizes, int n_in,
                              void* d_out, int out_size, void* d_ws, size_t ws_size,
                              hipStream_t stream) {
  const float* x  = (const float*)d_in[0];
  const float* Wq = (const float*)d_in[1];
  const float* Wk = (const float*)d_in[2];
  const float* Wv = (const float*)d_in[3];
  const float* Wo = (const float*)d_in[4];
  float* out = (float*)d_out;

  char* ws = (char*)d_ws;
  u16*   Xb     = (u16*)(ws + OFF_XB);
  u16*   Wcat   = (u16*)(ws + OFF_WCAT);
  u16*   Qb     = (u16*)(ws + OFF_QB);
  u16*   Kb     = (u16*)(ws + OFF_KB);
  float* Vf     = (float*)(ws + OFF_VF);
  float* rowsum = (float*)(ws + OFF_RS);
  float* rinv   = (float*)(ws + OFF_RINV);
  float* colacc = (float*)(ws + OFF_CA);
  float* p      = (float*)(ws + OFF_P);

  k_conv<<<(MTOK * DDIM / 8 + 255) / 256, 256, 0, stream>>>(x, Xb, MTOK * DDIM / 8);
  const int w8 = HDIM * DDIM / 8;
  k_conv<<<(w8 + 255) / 256, 256, 0, stream>>>(Wq, Wcat + 0 * HDIM * DDIM, w8);
  k_conv<<<(w8 + 255) / 256, 256, 0, stream>>>(Wk, Wcat + 1 * HDIM * DDIM, w8);
  k_conv<<<(w8 + 255) / 256, 256, 0, stream>>>(Wv, Wcat + 2 * HDIM * DDIM, w8);

  hipMemsetAsync(ws + OFF_RS, 0, WS_NEED - OFF_RS, stream);

  k_qkv<<<dim3(MTOK / 128, DDIM / 128), 256, 0, stream>>>(Xb, Wcat, Qb, Kb, Vf);

  k_spass<1><<<512, 512, 0, stream>>>(Qb, Kb, nullptr, rowsum);
  k_rinv<<<MTOK / 256, 256, 0, stream>>>(rowsum, rinv);
  k_spass<2><<<512, 512, 0, stream>>>(Qb, Kb, rinv, colacc);

  k_p<<<MTOK / 128, 256, 0, stream>>>(colacc, Vf, p);
  k_out<<<(DDIM + 255) / 256, 256, 0, stream>>>(p, Wo, out);
}

// Round 7
// 455.682 us; speedup vs baseline: 1.1774x; 1.1774x over previous
//
#include <hip/hip_runtime.h>

// ---------------------------------------------------------------------------
// AttnPool: out[1,768] = mean_rows( softmax(QK^T/16) @ V ) @ Wo^T
// M=16384, D=768, H=256.  a_bar[j] = (1/M) sum_m exp(S[m,j]/16)/rowsum[m];
// out = (a_bar @ V) @ Wo^T.
//
// R6 post-mortem: 256^2 flat tiling re-staged A 8x/block -> FETCH 215MB,
// fetch-latency-bound. R7: A panel (256 rows x full H=256 = 128KB) LDS-
// RESIDENT per block; B (K tiles) streamed dbuf 2x16KB. LDS = 160KB exactly.
// Grid 64 rp x 8 cg, cg == XCD (blockIdx%8): 64 blocks/XCD share one 1MB K
// slab in L2 (R5-proven locality). 64-step counted-vmcnt pipeline (R6-proven
// race-free): stage_B(s+1); vmcnt(2); barrier; ds_read+MFMA(setprio); barrier.
// T2 swizzle both-sides: A rows 512B key=(row&7)<<4; B rows 64B
// key=((row^(row>>2))&3)<<4 (2-way max = free).
// ---------------------------------------------------------------------------

typedef unsigned short u16;
typedef __attribute__((ext_vector_type(8))) unsigned short u16x8;
typedef __bf16 bf16x8 __attribute__((ext_vector_type(8)));
typedef float f32x4 __attribute__((ext_vector_type(4)));

#define AS1 __attribute__((address_space(1)))
#define AS3 __attribute__((address_space(3)))

#define MTOK 16384
#define DDIM 768
#define HDIM 256
#define SM_SCALE 0.0625f   // 1/sqrt(256)

// ---- workspace layout (bytes) ----
#define OFF_XB    (size_t)0                       // bf16 x      [M][768]
#define OFF_WCAT  (size_t)25165824                // bf16 Wcat   [768][768]
#define OFF_QB    (size_t)26345472                // bf16 Q      [M][256]
#define OFF_KB    (size_t)34734080                // bf16 K      [M][256]
#define OFF_VF    (size_t)43122688                // f32  V      [M][256]
#define OFF_RS    (size_t)59899904                // f32 rowsum  [M]
#define OFF_RINV  (size_t)59965440                // f32 rinv    [M]
#define OFF_CA    (size_t)60030976                // f32 colacc  [M]
#define OFF_P     (size_t)60096512                // f32 p       [256]
#define WS_NEED   (size_t)60097536

__device__ __forceinline__ u16 f2bf(float f) {
  union { float f; unsigned u; } v; v.f = f;
  unsigned r = v.u + 0x7fffu + ((v.u >> 16) & 1u);
  return (u16)(r >> 16);
}

// ---------------- fp32 -> bf16 conversion, 8 elems/thread -------------------
__global__ void k_conv(const float* __restrict__ src, u16* __restrict__ dst, int n8) {
  int i = blockIdx.x * blockDim.x + threadIdx.x;
  if (i >= n8) return;
  const float4* s = (const float4*)src;
  float4 a = s[2 * i], b = s[2 * i + 1];
  u16x8 o = { f2bf(a.x), f2bf(a.y), f2bf(a.z), f2bf(a.w),
              f2bf(b.x), f2bf(b.y), f2bf(b.z), f2bf(b.w) };
  *(u16x8*)(dst + (size_t)i * 8) = o;
}

// ===================== QKV projection (m97 structure, unchanged) ============
__device__ __forceinline__ void stage_tile(const u16* __restrict__ g, int ld,
                                           u16* lds, int wid, int lane) {
  const int r = lane >> 2;
  const int c = (lane & 3) * 8;
#pragma unroll
  for (int i = 0; i < 2; ++i) {
    int ii = wid * 2 + i;
    const u16* gp = g + (size_t)(ii * 16 + r) * ld + c;
    __builtin_amdgcn_global_load_lds((const AS1 unsigned int*)gp,
                                     (AS3 unsigned int*)(lds + ii * 512), 16, 0, 0);
  }
}

#define KSTEP(APTR, LDA, BPTR, LDB)                                           \
  {                                                                           \
    stage_tile((APTR), (LDA), As, wid, lane);                                 \
    stage_tile((BPTR), (LDB), Bs, wid, lane);                                 \
    __syncthreads();                                                          \
    bf16x8 af[4], bfr[4];                                                     \
    const int kk = (lane >> 4) * 8;                                           \
    _Pragma("unroll") for (int m = 0; m < 4; ++m)                             \
        af[m] = *(const bf16x8*)(As + (wm * 64 + m * 16 + (lane & 15)) * 32 + kk); \
    _Pragma("unroll") for (int n = 0; n < 4; ++n)                             \
        bfr[n] = *(const bf16x8*)(Bs + (wn * 64 + n * 16 + (lane & 15)) * 32 + kk); \
    _Pragma("unroll") for (int m = 0; m < 4; ++m)                             \
        _Pragma("unroll") for (int n = 0; n < 4; ++n)                         \
            acc[m][n] = __builtin_amdgcn_mfma_f32_16x16x32_bf16(              \
                af[m], bfr[n], acc[m][n], 0, 0, 0);                           \
    __syncthreads();                                                          \
  }

__global__ __launch_bounds__(256, 2) void k_qkv(const u16* __restrict__ Xb,
                                                const u16* __restrict__ Wcat,
                                                u16* __restrict__ Qb,
                                                u16* __restrict__ Kb,
                                                float* __restrict__ Vf) {
  __shared__ u16 As[128 * 32];
  __shared__ u16 Bs[128 * 32];
  const int tid = threadIdx.x, wid = tid >> 6, lane = tid & 63;
  const int wm = wid >> 1, wn = wid & 1;
  const int row0 = blockIdx.x * 128;
  const int col0 = blockIdx.y * 128;
  f32x4 acc[4][4] = {};
  for (int k0 = 0; k0 < DDIM; k0 += 32) {
    KSTEP(Xb + (size_t)row0 * DDIM + k0, DDIM,
          Wcat + (size_t)col0 * DDIM + k0, DDIM);
  }
#pragma unroll
  for (int m = 0; m < 4; ++m)
#pragma unroll
    for (int n = 0; n < 4; ++n) {
      int col = col0 + wn * 64 + n * 16 + (lane & 15);
#pragma unroll
      for (int j = 0; j < 4; ++j) {
        int row = row0 + wm * 64 + m * 16 + (lane >> 4) * 4 + j;
        float v = acc[m][n][j];
        if (col < 256)      Qb[(size_t)row * HDIM + col]         = f2bf(v);
        else if (col < 512) Kb[(size_t)row * HDIM + (col - 256)] = f2bf(v);
        else                Vf[(size_t)row * HDIM + (col - 512)] = v;
      }
    }
}

// ===================== S-pass v2: A-resident, B-streaming pipeline ==========
// Block 512 thr (8 waves, wave grid 2M x 4N; per-wave out 128 x 64 per ct).
// LDS 160KB: A[256 rows][256 H] bf16 swizzled (128KB) + B dbuf 2 x
// [256 rows][32 H] (2x16KB). 64 pipeline steps = 8 ct-tiles x 8 H-steps.
// Per step/wave: 4 B-frag + 8 A-frag ds_read_b128, 32 MFMA, 2-inst B stage.

template <int PASS>
__global__ __launch_bounds__(512, 2) void k_spass(const u16* __restrict__ Qb,
                                                  const u16* __restrict__ Kb,
                                                  const float* __restrict__ rinv,
                                                  float* __restrict__ dst) {
  __shared__ u16 sh[81920];                 // 160KB exactly
  const int tid = threadIdx.x, wid = tid >> 6, lane = tid & 63;
  const int wm = wid >> 2, wn = wid & 3;
  const int rp = blockIdx.x >> 3;           // row-panel 0..63
  const int cg = blockIdx.x & 7;            // col-group == XCD

  const int l15 = lane & 15;
  // read-side swizzle constants
  const int akey = (lane & 7) << 4;                          // A: rows 512B
  const int bkey = ((l15 ^ (l15 >> 2)) & 3) << 4;            // B: rows 64B
  const int bcol = (((lane >> 4) * 16) ^ bkey) >> 1;         // u16 units
  // stage-side (inverse) swizzle lane constants
  const int a_srow = lane >> 5;
  const int a_scol = (lane & 31) * 16;
  const int b_srow = lane >> 2;
  const int b_scol = ((lane & 3) * 16) ^ ((((lane >> 2) & 3) ^ ((lane >> 4) & 3)) << 4);

  f32x4 acc[8][4] = {};
  float aux[8][4];                          // PASS1: exp-sums; PASS2: rinv
#pragma unroll
  for (int mi = 0; mi < 8; ++mi)
#pragma unroll
    for (int j = 0; j < 4; ++j)
      aux[mi][j] = (PASS == 1) ? 0.0f
          : rinv[rp * 256 + wm * 128 + mi * 16 + (lane >> 4) * 4 + j];

  // ---- stage A panel once (128 insts block-wide, 16 per wave) ----
  {
    const char* gA = (const char*)Qb + (size_t)(rp * 256) * 512;
#pragma unroll
    for (int j = 0; j < 16; ++j) {
      const int i = wid * 16 + j;
      const int row = i * 2 + a_srow;
      const char* src = gA + (size_t)row * 512 + (a_scol ^ ((row & 7) << 4));
      __builtin_amdgcn_global_load_lds((const AS1 unsigned int*)src,
                                       (AS3 unsigned int*)(sh + i * 512), 16, 0, 0);
    }
  }

#define STAGE_B(S)                                                            \
  {                                                                           \
    const int ct_ = cg * 8 + ((S) >> 3), t_ = (S) & 7;                        \
    const char* gB = (const char*)Kb + (size_t)(ct_ * 256) * 512 + t_ * 64;   \
    u16* dl = sh + 65536 + ((S) & 1) * 8192;                                  \
    _Pragma("unroll") for (int j = 0; j < 2; ++j) {                           \
      const int i = wid * 2 + j;                                              \
      const char* src = gB + (size_t)(i * 16 + b_srow) * 512 + b_scol;        \
      __builtin_amdgcn_global_load_lds((const AS1 unsigned int*)src,          \
                                       (AS3 unsigned int*)(dl + i * 512), 16, 0, 0); \
    }                                                                         \
  }

  STAGE_B(0);

  for (int s = 0; s < 64; ++s) {
    if (s + 1 < 64) {
      STAGE_B(s + 1);
      asm volatile("s_waitcnt vmcnt(2)" ::: "memory");  // A + B(s) landed
    } else {
      asm volatile("s_waitcnt vmcnt(0)" ::: "memory");
    }
    __builtin_amdgcn_s_barrier();

    const int t = s & 7;
    const u16* Bb = sh + 65536 + (s & 1) * 8192;
    const int acolt = ((t * 64 + (lane >> 4) * 16) ^ akey) >> 1;  // u16 units

    bf16x8 bq[4];
#pragma unroll
    for (int ni = 0; ni < 4; ++ni)
      bq[ni] = *(const bf16x8*)(Bb + (wn * 64 + ni * 16 + l15) * 32 + bcol);

    __builtin_amdgcn_s_setprio(1);
#pragma unroll
    for (int mi = 0; mi < 8; ++mi) {
      bf16x8 a0 = *(const bf16x8*)(sh + (wm * 128 + mi * 16 + l15) * 256 + acolt);
#pragma unroll
      for (int ni = 0; ni < 4; ++ni)
        acc[mi][ni] = __builtin_amdgcn_mfma_f32_16x16x32_bf16(a0, bq[ni], acc[mi][ni], 0, 0, 0);
    }
    __builtin_amdgcn_s_setprio(0);
    __builtin_amdgcn_s_barrier();

    if ((s & 7) == 7) {                     // ct epilogue (register-only + atomics)
      if (PASS == 1) {
#pragma unroll
        for (int mi = 0; mi < 8; ++mi)
#pragma unroll
          for (int ni = 0; ni < 4; ++ni)
#pragma unroll
            for (int j = 0; j < 4; ++j)
              aux[mi][j] += __expf(acc[mi][ni][j] * SM_SCALE);
      } else {
        const int ct = cg * 8 + (s >> 3);
        float cs[4] = {};
#pragma unroll
        for (int mi = 0; mi < 8; ++mi)
#pragma unroll
          for (int ni = 0; ni < 4; ++ni)
#pragma unroll
            for (int j = 0; j < 4; ++j)
              cs[ni] += __expf(acc[mi][ni][j] * SM_SCALE) * aux[mi][j];
#pragma unroll
        for (int ni = 0; ni < 4; ++ni) {
          float v = cs[ni];
          v += __shfl_xor(v, 16);
          v += __shfl_xor(v, 32);
          if ((lane >> 4) == 0)
            atomicAdd(&dst[ct * 256 + wn * 64 + ni * 16 + l15], v);
        }
      }
#pragma unroll
      for (int mi = 0; mi < 8; ++mi)
#pragma unroll
        for (int ni = 0; ni < 4; ++ni)
          acc[mi][ni] = (f32x4){0.f, 0.f, 0.f, 0.f};
    }
  }

  if (PASS == 1) {
#pragma unroll
    for (int mi = 0; mi < 8; ++mi)
#pragma unroll
      for (int j = 0; j < 4; ++j) {
        float v = aux[mi][j];
        v += __shfl_xor(v, 1);  v += __shfl_xor(v, 2);
        v += __shfl_xor(v, 4);  v += __shfl_xor(v, 8);
        if (l15 == 0)
          atomicAdd(&dst[rp * 256 + wm * 128 + mi * 16 + (lane >> 4) * 4 + j], v);
      }
  }
}

__global__ void k_rinv(const float* __restrict__ rowsum, float* __restrict__ rinv) {
  int i = blockIdx.x * 256 + threadIdx.x;
  if (i < MTOK) rinv[i] = 1.0f / (rowsum[i] * (float)MTOK);
}

// --------------------- tail reductions --------------------------------------
__global__ void k_p(const float* __restrict__ colacc, const float* __restrict__ Vf,
                    float* __restrict__ p) {
  const int h = threadIdx.x;
  const int r0 = blockIdx.x * 128;
  float s = 0.f;
  for (int r = r0; r < r0 + 128; ++r)
    s += colacc[r] * Vf[(size_t)r * HDIM + h];
  atomicAdd(&p[h], s);
}

__global__ void k_out(const float* __restrict__ p, const float* __restrict__ Wo,
                      float* __restrict__ out) {
  const int d = blockIdx.x * 256 + threadIdx.x;
  if (d >= DDIM) return;
  float s = 0.f;
  for (int h = 0; h < HDIM; ++h) s += p[h] * Wo[(size_t)d * HDIM + h];
  out[d] = s;
}

// ---------------------------------------------------------------------------
extern "C" void kernel_launch(void* const* d_in, const int* in_sizes, int n_in,
                              void* d_out, int out_size, void* d_ws, size_t ws_size,
                              hipStream_t stream) {
  const float* x  = (const float*)d_in[0];
  const float* Wq = (const float*)d_in[1];
  const float* Wk = (const float*)d_in[2];
  const float* Wv = (const float*)d_in[3];
  const float* Wo = (const float*)d_in[4];
  float* out = (float*)d_out;

  char* ws = (char*)d_ws;
  u16*   Xb     = (u16*)(ws + OFF_XB);
  u16*   Wcat   = (u16*)(ws + OFF_WCAT);
  u16*   Qb     = (u16*)(ws + OFF_QB);
  u16*   Kb     = (u16*)(ws + OFF_KB);
  float* Vf     = (float*)(ws + OFF_VF);
  float* rowsum = (float*)(ws + OFF_RS);
  float* rinv   = (float*)(ws + OFF_RINV);
  float* colacc = (float*)(ws + OFF_CA);
  float* p      = (float*)(ws + OFF_P);

  k_conv<<<(MTOK * DDIM / 8 + 255) / 256, 256, 0, stream>>>(x, Xb, MTOK * DDIM / 8);
  const int w8 = HDIM * DDIM / 8;
  k_conv<<<(w8 + 255) / 256, 256, 0, stream>>>(Wq, Wcat + 0 * HDIM * DDIM, w8);
  k_conv<<<(w8 + 255) / 256, 256, 0, stream>>>(Wk, Wcat + 1 * HDIM * DDIM, w8);
  k_conv<<<(w8 + 255) / 256, 256, 0, stream>>>(Wv, Wcat + 2 * HDIM * DDIM, w8);

  hipMemsetAsync(ws + OFF_RS, 0, WS_NEED - OFF_RS, stream);

  k_qkv<<<dim3(MTOK / 128, DDIM / 128), 256, 0, stream>>>(Xb, Wcat, Qb, Kb, Vf);

  k_spass<1><<<512, 512, 0, stream>>>(Qb, Kb, nullptr, rowsum);
  k_rinv<<<MTOK / 256, 256, 0, stream>>>(rowsum, rinv);
  k_spass<2><<<512, 512, 0, stream>>>(Qb, Kb, rinv, colacc);

  k_p<<<MTOK / 128, 256, 0, stream>>>(colacc, Vf, p);
  k_out<<<(DDIM + 255) / 256, 256, 0, stream>>>(p, Wo, out);
}

// Round 11
// 455.406 us; speedup vs baseline: 1.1781x; 1.0006x over previous
//
#include <hip/hip_runtime.h>

// ---------------------------------------------------------------------------
// AttnPool: out[1,768] = mean_rows( softmax(QK^T/16) @ V ) @ Wo^T
// M=16384, D=768, H=256.
// R7: A-resident/B-stream S-pass, 178.6us each, MfmaUtil 33% (LDS-read-BW +
// residual conflict bound). R8: compute S ONCE — pass1 stores raw S (bf16,
// fragment-order, lane-major coalesced); pass2 becomes a streaming
// exp*rinv col-reduce (no LDS/MFMA). Host branch on ws_size (needs 597MB);
// fallback = exact R7 two-pass recompute.
// ---------------------------------------------------------------------------

typedef unsigned short u16;
typedef __attribute__((ext_vector_type(8))) unsigned short u16x8;
typedef __bf16 bf16x8 __attribute__((ext_vector_type(8)));
typedef float f32x4 __attribute__((ext_vector_type(4)));

#define AS1 __attribute__((address_space(1)))
#define AS3 __attribute__((address_space(3)))

#define MTOK 16384
#define DDIM 768
#define HDIM 256
#define SM_SCALE 0.0625f   // 1/sqrt(256)

// ---- workspace layout (bytes) ----
#define OFF_XB    (size_t)0                       // bf16 x      [M][768]
#define OFF_WCAT  (size_t)25165824                // bf16 Wcat   [768][768]
#define OFF_QB    (size_t)26345472                // bf16 Q      [M][256]
#define OFF_KB    (size_t)34734080                // bf16 K      [M][256]
#define OFF_VF    (size_t)43122688                // f32  V      [M][256]
#define OFF_RS    (size_t)59899904                // f32 rowsum  [M]
#define OFF_RINV  (size_t)59965440                // f32 rinv    [M]
#define OFF_CA    (size_t)60030976                // f32 colacc  [M]
#define OFF_P     (size_t)60096512                // f32 p       [256]
#define WS_NEED   (size_t)60097536
#define OFF_S     WS_NEED                         // bf16 S, fragment order
#define WS_NEED_F (size_t)(WS_NEED + 536870912)   // 596,968,448

__device__ __forceinline__ u16 f2bf(float f) {
  union { float f; unsigned u; } v; v.f = f;
  unsigned r = v.u + 0x7fffu + ((v.u >> 16) & 1u);
  return (u16)(r >> 16);
}
__device__ __forceinline__ float bf2f(u16 b) {
  union { unsigned u; float f; } v; v.u = ((unsigned)b) << 16;
  return v.f;
}

// ---------------- fp32 -> bf16 conversion, 8 elems/thread -------------------
__global__ void k_conv(const float* __restrict__ src, u16* __restrict__ dst, int n8) {
  int i = blockIdx.x * blockDim.x + threadIdx.x;
  if (i >= n8) return;
  const float4* s = (const float4*)src;
  float4 a = s[2 * i], b = s[2 * i + 1];
  u16x8 o = { f2bf(a.x), f2bf(a.y), f2bf(a.z), f2bf(a.w),
              f2bf(b.x), f2bf(b.y), f2bf(b.z), f2bf(b.w) };
  *(u16x8*)(dst + (size_t)i * 8) = o;
}

// ===================== QKV projection (m97 structure, unchanged) ============
__device__ __forceinline__ void stage_tile(const u16* __restrict__ g, int ld,
                                           u16* lds, int wid, int lane) {
  const int r = lane >> 2;
  const int c = (lane & 3) * 8;
#pragma unroll
  for (int i = 0; i < 2; ++i) {
    int ii = wid * 2 + i;
    const u16* gp = g + (size_t)(ii * 16 + r) * ld + c;
    __builtin_amdgcn_global_load_lds((const AS1 unsigned int*)gp,
                                     (AS3 unsigned int*)(lds + ii * 512), 16, 0, 0);
  }
}

#define KSTEP(APTR, LDA, BPTR, LDB)                                           \
  {                                                                           \
    stage_tile((APTR), (LDA), As, wid, lane);                                 \
    stage_tile((BPTR), (LDB), Bs, wid, lane);                                 \
    __syncthreads();                                                          \
    bf16x8 af[4], bfr[4];                                                     \
    const int kk = (lane >> 4) * 8;                                           \
    _Pragma("unroll") for (int m = 0; m < 4; ++m)                             \
        af[m] = *(const bf16x8*)(As + (wm * 64 + m * 16 + (lane & 15)) * 32 + kk); \
    _Pragma("unroll") for (int n = 0; n < 4; ++n)                             \
        bfr[n] = *(const bf16x8*)(Bs + (wn * 64 + n * 16 + (lane & 15)) * 32 + kk); \
    _Pragma("unroll") for (int m = 0; m < 4; ++m)                             \
        _Pragma("unroll") for (int n = 0; n < 4; ++n)                         \
            acc[m][n] = __builtin_amdgcn_mfma_f32_16x16x32_bf16(              \
                af[m], bfr[n], acc[m][n], 0, 0, 0);                           \
    __syncthreads();                                                          \
  }

__global__ __launch_bounds__(256, 2) void k_qkv(const u16* __restrict__ Xb,
                                                const u16* __restrict__ Wcat,
                                                u16* __restrict__ Qb,
                                                u16* __restrict__ Kb,
                                                float* __restrict__ Vf) {
  __shared__ u16 As[128 * 32];
  __shared__ u16 Bs[128 * 32];
  const int tid = threadIdx.x, wid = tid >> 6, lane = tid & 63;
  const int wm = wid >> 1, wn = wid & 1;
  const int row0 = blockIdx.x * 128;
  const int col0 = blockIdx.y * 128;
  f32x4 acc[4][4] = {};
  for (int k0 = 0; k0 < DDIM; k0 += 32) {
    KSTEP(Xb + (size_t)row0 * DDIM + k0, DDIM,
          Wcat + (size_t)col0 * DDIM + k0, DDIM);
  }
#pragma unroll
  for (int m = 0; m < 4; ++m)
#pragma unroll
    for (int n = 0; n < 4; ++n) {
      int col = col0 + wn * 64 + n * 16 + (lane & 15);
#pragma unroll
      for (int j = 0; j < 4; ++j) {
        int row = row0 + wm * 64 + m * 16 + (lane >> 4) * 4 + j;
        float v = acc[m][n][j];
        if (col < 256)      Qb[(size_t)row * HDIM + col]         = f2bf(v);
        else if (col < 512) Kb[(size_t)row * HDIM + (col - 256)] = f2bf(v);
        else                Vf[(size_t)row * HDIM + (col - 512)] = v;
      }
    }
}

// ===================== S-pass: A-resident, B-streaming pipeline =============
// (R7 structure, verified).  STORE=true additionally writes raw S (bf16) in
// fragment order: chunk16B index = (((blk*8+wid)*128 + (ct*8+mi)*2 + h)*64
// + lane), h=0 -> ni{0,1}, h=1 -> ni{2,3}; lane-major => coalesced 1KB/inst.

template <int PASS, bool STORE>
__global__ __launch_bounds__(512, 2) void k_spass(const u16* __restrict__ Qb,
                                                  const u16* __restrict__ Kb,
                                                  const float* __restrict__ rinv,
                                                  float* __restrict__ dst,
                                                  u16* __restrict__ Sp) {
  __shared__ u16 sh[81920];                 // 160KB exactly
  const int tid = threadIdx.x, wid = tid >> 6, lane = tid & 63;
  const int wm = wid >> 2, wn = wid & 3;
  const int rp = blockIdx.x >> 3;           // row-panel 0..63
  const int cg = blockIdx.x & 7;            // col-group == XCD

  const int l15 = lane & 15;
  // read-side swizzle constants
  const int akey = (lane & 7) << 4;                          // A: rows 512B
  const int bkey = ((l15 ^ (l15 >> 2)) & 3) << 4;            // B: rows 64B
  const int bcol = (((lane >> 4) * 16) ^ bkey) >> 1;         // u16 units
  // stage-side (inverse) swizzle lane constants
  const int a_srow = lane >> 5;
  const int a_scol = (lane & 31) * 16;
  const int b_srow = lane >> 2;
  const int b_scol = ((lane & 3) * 16) ^ ((((lane >> 2) & 3) ^ ((lane >> 4) & 3)) << 4);

  f32x4 acc[8][4] = {};
  float aux[8][4];                          // PASS1: exp-sums; PASS2: rinv
#pragma unroll
  for (int mi = 0; mi < 8; ++mi)
#pragma unroll
    for (int j = 0; j < 4; ++j)
      aux[mi][j] = (PASS == 1) ? 0.0f
          : rinv[rp * 256 + wm * 128 + mi * 16 + (lane >> 4) * 4 + j];

  // ---- stage A panel once ----
  {
    const char* gA = (const char*)Qb + (size_t)(rp * 256) * 512;
#pragma unroll
    for (int j = 0; j < 16; ++j) {
      const int i = wid * 16 + j;
      const int row = i * 2 + a_srow;
      const char* src = gA + (size_t)row * 512 + (a_scol ^ ((row & 7) << 4));
      __builtin_amdgcn_global_load_lds((const AS1 unsigned int*)src,
                                       (AS3 unsigned int*)(sh + i * 512), 16, 0, 0);
    }
  }

#define STAGE_B(S)                                                            \
  {                                                                           \
    const int ct_ = cg * 8 + ((S) >> 3), t_ = (S) & 7;                        \
    const char* gB = (const char*)Kb + (size_t)(ct_ * 256) * 512 + t_ * 64;   \
    u16* dl = sh + 65536 + ((S) & 1) * 8192;                                  \
    _Pragma("unroll") for (int j = 0; j < 2; ++j) {                           \
      const int i = wid * 2 + j;                                              \
      const char* src = gB + (size_t)(i * 16 + b_srow) * 512 + b_scol;        \
      __builtin_amdgcn_global_load_lds((const AS1 unsigned int*)src,          \
                                       (AS3 unsigned int*)(dl + i * 512), 16, 0, 0); \
    }                                                                         \
  }

  STAGE_B(0);

  for (int s = 0; s < 64; ++s) {
    if (s + 1 < 64) {
      STAGE_B(s + 1);
      asm volatile("s_waitcnt vmcnt(2)" ::: "memory");
    } else {
      asm volatile("s_waitcnt vmcnt(0)" ::: "memory");
    }
    __builtin_amdgcn_s_barrier();

    const int t = s & 7;
    const u16* Bb = sh + 65536 + (s & 1) * 8192;
    const int acolt = ((t * 64 + (lane >> 4) * 16) ^ akey) >> 1;  // u16 units

    bf16x8 bq[4];
#pragma unroll
    for (int ni = 0; ni < 4; ++ni)
      bq[ni] = *(const bf16x8*)(Bb + (wn * 64 + ni * 16 + l15) * 32 + bcol);

    __builtin_amdgcn_s_setprio(1);
#pragma unroll
    for (int mi = 0; mi < 8; ++mi) {
      bf16x8 a0 = *(const bf16x8*)(sh + (wm * 128 + mi * 16 + l15) * 256 + acolt);
#pragma unroll
      for (int ni = 0; ni < 4; ++ni)
        acc[mi][ni] = __builtin_amdgcn_mfma_f32_16x16x32_bf16(a0, bq[ni], acc[mi][ni], 0, 0, 0);
    }
    __builtin_amdgcn_s_setprio(0);

    if ((s & 7) == 7) {                     // ct epilogue (register-only + stores)
      const int ct = s >> 3;
      if (PASS == 1) {
#pragma unroll
        for (int mi = 0; mi < 8; ++mi) {
          if (STORE) {
            const size_t bw = (size_t)blockIdx.x * 8 + wid;
            u16x8 h0 = { f2bf(acc[mi][0][0]), f2bf(acc[mi][0][1]),
                         f2bf(acc[mi][0][2]), f2bf(acc[mi][0][3]),
                         f2bf(acc[mi][1][0]), f2bf(acc[mi][1][1]),
                         f2bf(acc[mi][1][2]), f2bf(acc[mi][1][3]) };
            u16x8 h1 = { f2bf(acc[mi][2][0]), f2bf(acc[mi][2][1]),
                         f2bf(acc[mi][2][2]), f2bf(acc[mi][2][3]),
                         f2bf(acc[mi][3][0]), f2bf(acc[mi][3][1]),
                         f2bf(acc[mi][3][2]), f2bf(acc[mi][3][3]) };
            *(u16x8*)(Sp + ((bw * 128 + (ct * 8 + mi) * 2 + 0) * 64 + lane) * 8) = h0;
            *(u16x8*)(Sp + ((bw * 128 + (ct * 8 + mi) * 2 + 1) * 64 + lane) * 8) = h1;
          }
#pragma unroll
          for (int ni = 0; ni < 4; ++ni)
#pragma unroll
            for (int j = 0; j < 4; ++j)
              aux[mi][j] += __expf(acc[mi][ni][j] * SM_SCALE);
        }
      } else {
        const int CT = cg * 8 + ct;
        float cs[4] = {};
#pragma unroll
        for (int mi = 0; mi < 8; ++mi)
#pragma unroll
          for (int ni = 0; ni < 4; ++ni)
#pragma unroll
            for (int j = 0; j < 4; ++j)
              cs[ni] += __expf(acc[mi][ni][j] * SM_SCALE) * aux[mi][j];
#pragma unroll
        for (int ni = 0; ni < 4; ++ni) {
          float v = cs[ni];
          v += __shfl_xor(v, 16);
          v += __shfl_xor(v, 32);
          if ((lane >> 4) == 0)
            atomicAdd(&dst[CT * 256 + wn * 64 + ni * 16 + l15], v);
        }
      }
#pragma unroll
      for (int mi = 0; mi < 8; ++mi)
#pragma unroll
        for (int ni = 0; ni < 4; ++ni)
          acc[mi][ni] = (f32x4){0.f, 0.f, 0.f, 0.f};
    }
    __builtin_amdgcn_s_barrier();           // all reads of buf[s&1] done
  }

  if (PASS == 1) {
#pragma unroll
    for (int mi = 0; mi < 8; ++mi)
#pragma unroll
      for (int j = 0; j < 4; ++j) {
        float v = aux[mi][j];
        v += __shfl_xor(v, 1);  v += __shfl_xor(v, 2);
        v += __shfl_xor(v, 4);  v += __shfl_xor(v, 8);
        if (l15 == 0)
          atomicAdd(&dst[rp * 256 + wm * 128 + mi * 16 + (lane >> 4) * 4 + j], v);
      }
  }
}

// ============ pass-2 reader: streaming exp(S)*rinv column reduce ============
__global__ __launch_bounds__(512) void k_s2r(const u16* __restrict__ Sp,
                                             const float* __restrict__ rinv,
                                             float* __restrict__ colacc) {
  const int tid = threadIdx.x, wid = tid >> 6, lane = tid & 63;
  const int wm = wid >> 2, wn = wid & 3;
  const int rp = blockIdx.x >> 3;
  const int cg = blockIdx.x & 7;
  const int l15 = lane & 15;

  float aux[8][4];
#pragma unroll
  for (int mi = 0; mi < 8; ++mi)
#pragma unroll
    for (int j = 0; j < 4; ++j)
      aux[mi][j] = rinv[rp * 256 + wm * 128 + mi * 16 + (lane >> 4) * 4 + j];

  const size_t bw = (size_t)blockIdx.x * 8 + wid;
  for (int ct = 0; ct < 8; ++ct) {
    float cs[4] = {};
#pragma unroll
    for (int mi = 0; mi < 8; ++mi) {
      u16x8 h0 = *(const u16x8*)(Sp + ((bw * 128 + (ct * 8 + mi) * 2 + 0) * 64 + lane) * 8);
      u16x8 h1 = *(const u16x8*)(Sp + ((bw * 128 + (ct * 8 + mi) * 2 + 1) * 64 + lane) * 8);
#pragma unroll
      for (int j = 0; j < 4; ++j) {
        cs[0] += __expf(bf2f(h0[j])     * SM_SCALE) * aux[mi][j];
        cs[1] += __expf(bf2f(h0[4 + j]) * SM_SCALE) * aux[mi][j];
        cs[2] += __expf(bf2f(h1[j])     * SM_SCALE) * aux[mi][j];
        cs[3] += __expf(bf2f(h1[4 + j]) * SM_SCALE) * aux[mi][j];
      }
    }
    const int CT = cg * 8 + ct;
#pragma unroll
    for (int ni = 0; ni < 4; ++ni) {
      float v = cs[ni];
      v += __shfl_xor(v, 16);
      v += __shfl_xor(v, 32);
      if ((lane >> 4) == 0)
        atomicAdd(&colacc[CT * 256 + wn * 64 + ni * 16 + l15], v);
    }
  }
}

__global__ void k_rinv(const float* __restrict__ rowsum, float* __restrict__ rinv) {
  int i = blockIdx.x * 256 + threadIdx.x;
  if (i < MTOK) rinv[i] = 1.0f / (rowsum[i] * (float)MTOK);
}

// --------------------- tail reductions --------------------------------------
__global__ void k_p(const float* __restrict__ colacc, const float* __restrict__ Vf,
                    float* __restrict__ p) {
  const int h = threadIdx.x;
  const int r0 = blockIdx.x * 128;
  float s = 0.f;
  for (int r = r0; r < r0 + 128; ++r)
    s += colacc[r] * Vf[(size_t)r * HDIM + h];
  atomicAdd(&p[h], s);
}

__global__ void k_out(const float* __restrict__ p, const float* __restrict__ Wo,
                      float* __restrict__ out) {
  const int d = blockIdx.x * 256 + threadIdx.x;
  if (d >= DDIM) return;
  float s = 0.f;
  for (int h = 0; h < HDIM; ++h) s += p[h] * Wo[(size_t)d * HDIM + h];
  out[d] = s;
}

// ---------------------------------------------------------------------------
extern "C" void kernel_launch(void* const* d_in, const int* in_sizes, int n_in,
                              void* d_out, int out_size, void* d_ws, size_t ws_size,
                              hipStream_t stream) {
  const float* x  = (const float*)d_in[0];
  const float* Wq = (const float*)d_in[1];
  const float* Wk = (const float*)d_in[2];
  const float* Wv = (const float*)d_in[3];
  const float* Wo = (const float*)d_in[4];
  float* out = (float*)d_out;

  char* ws = (char*)d_ws;
  u16*   Xb     = (u16*)(ws + OFF_XB);
  u16*   Wcat   = (u16*)(ws + OFF_WCAT);
  u16*   Qb     = (u16*)(ws + OFF_QB);
  u16*   Kb     = (u16*)(ws + OFF_KB);
  float* Vf     = (float*)(ws + OFF_VF);
  float* rowsum = (float*)(ws + OFF_RS);
  float* rinv   = (float*)(ws + OFF_RINV);
  float* colacc = (float*)(ws + OFF_CA);
  float* p      = (float*)(ws + OFF_P);
  u16*   Sp     = (u16*)(ws + OFF_S);

  const bool fused = (ws_size >= WS_NEED_F);

  k_conv<<<(MTOK * DDIM / 8 + 255) / 256, 256, 0, stream>>>(x, Xb, MTOK * DDIM / 8);
  const int w8 = HDIM * DDIM / 8;
  k_conv<<<(w8 + 255) / 256, 256, 0, stream>>>(Wq, Wcat + 0 * HDIM * DDIM, w8);
  k_conv<<<(w8 + 255) / 256, 256, 0, stream>>>(Wk, Wcat + 1 * HDIM * DDIM, w8);
  k_conv<<<(w8 + 255) / 256, 256, 0, stream>>>(Wv, Wcat + 2 * HDIM * DDIM, w8);

  hipMemsetAsync(ws + OFF_RS, 0, WS_NEED - OFF_RS, stream);

  k_qkv<<<dim3(MTOK / 128, DDIM / 128), 256, 0, stream>>>(Xb, Wcat, Qb, Kb, Vf);

  if (fused) {
    k_spass<1, true><<<512, 512, 0, stream>>>(Qb, Kb, nullptr, rowsum, Sp);
    k_rinv<<<MTOK / 256, 256, 0, stream>>>(rowsum, rinv);
    k_s2r<<<512, 512, 0, stream>>>(Sp, rinv, colacc);
  } else {
    k_spass<1, false><<<512, 512, 0, stream>>>(Qb, Kb, nullptr, rowsum, nullptr);
    k_rinv<<<MTOK / 256, 256, 0, stream>>>(rowsum, rinv);
    k_spass<2, false><<<512, 512, 0, stream>>>(Qb, Kb, rinv, colacc, nullptr);
  }

  k_p<<<MTOK / 128, 256, 0, stream>>>(colacc, Vf, p);
  k_out<<<(DDIM + 255) / 256, 256, 0, stream>>>(p, Wo, out);
}